// Round 1
// baseline (788.986 us; speedup 1.0000x reference)
//
#include <hip/hip_runtime.h>

// RecNN on a perfect binary forest: u = relu(contents @ W_u^T + b_u), then 10
// levels of emb = relu([emb_L, emb_R, u_j] @ W_h^T + b_h).
// All GEMMs run as bf16 MFMA (16x16x32) with fp32 accumulation; activations
// stored bf16 in workspace. Threshold is 2% of ref absmax -> bf16 is safe.
//
// GEMM structure = learn_hip m97: 128x128 block tile, BK=32, 256 threads
// (4 waves, each 64x64 via 4x4 frags), global_load_lds width=16 staging.
// MODE 0: A is fp32 (contents), converted in-register during staging.
// MODE 1: A rows gathered from 3 segments (emb[idx.x] | emb[idx.y] | u_j);
//         each BK=32 step lies entirely within one 512-wide segment, so the
//         segment choice is k-loop-uniform.

typedef unsigned short u16;
typedef __attribute__((ext_vector_type(8))) short bf16x8;
typedef __attribute__((ext_vector_type(4))) float f32x4;

#define TILE 128
#define BK 32

__device__ __forceinline__ u16 f2b(float f) {
  union { float f; unsigned u; } c; c.f = f;
  unsigned u = c.u;
  return (u16)((u + 0x7fffu + ((u >> 16) & 1u)) >> 16);  // RNE
}

__device__ __forceinline__ float b2f(unsigned hi16) {
  union { float f; unsigned u; } c; c.u = hi16 << 16; return c.f;
}

__device__ __forceinline__ void glds16(const void* g, void* l) {
  __builtin_amdgcn_global_load_lds(
      (__attribute__((address_space(1))) void*)g,
      (__attribute__((address_space(3))) void*)l, 16, 0, 0);
}

// MODE: 0 = A fp32 (convert during staging), 1 = gathered bf16 A
template <int MODE>
__global__ __launch_bounds__(256)
void gemm_bt(const float* __restrict__ Af32,
             const u16* __restrict__ embPrev,
             const u16* __restrict__ uLvl,
             const int2* __restrict__ idx,
             const u16* __restrict__ W,     // [512][K] bf16 (B^T layout)
             const float* __restrict__ bias,
             u16* __restrict__ out,         // [M][512] bf16
             int M, int K) {
  __shared__ __align__(16) u16 lA[TILE * BK];
  __shared__ __align__(16) u16 lB[TILE * BK];

  const int tid  = threadIdx.x;
  const int lane = tid & 63;
  const int wv   = tid >> 6;
  const int wrow = wv >> 1, wcol = wv & 1;
  const int mBase = blockIdx.y * TILE;
  const int n0    = blockIdx.x * TILE;

  // Staging geometry: slot off = r*256+tid covers LDS bytes off*16;
  // logical row = off>>2 (32 bf16 per row), quarter q = off&3 (8 bf16 each).
  const int rowA0 = tid >> 2;       // 0..63  (round 0)
  const int rowA1 = rowA0 + 64;     // 64..127 (round 1)
  const int q     = tid & 3;

  const float* af0 = nullptr; const float* af1 = nullptr;
  const u16 *aL0 = nullptr, *aR0 = nullptr, *aU0 = nullptr;
  const u16 *aL1 = nullptr, *aR1 = nullptr, *aU1 = nullptr;
  {
    int m0 = min(mBase + rowA0, M - 1);
    int m1 = min(mBase + rowA1, M - 1);
    if (MODE == 0) {
      af0 = Af32 + (size_t)m0 * K;
      af1 = Af32 + (size_t)m1 * K;
    } else {
      int2 c0 = idx[m0], c1 = idx[m1];
      aL0 = embPrev + (size_t)c0.x * 512;
      aR0 = embPrev + (size_t)c0.y * 512;
      aU0 = uLvl    + (size_t)m0   * 512;
      aL1 = embPrev + (size_t)c1.x * 512;
      aR1 = embPrev + (size_t)c1.y * 512;
      aU1 = uLvl    + (size_t)m1   * 512;
    }
  }
  const u16* bp0 = W + (size_t)(n0 + rowA0) * K;
  const u16* bp1 = W + (size_t)(n0 + rowA1) * K;

  f32x4 acc[4][4] = {};

  const int fm = lane & 15;
  const int kk = (lane >> 4) * 8;

  for (int k0 = 0; k0 < K; k0 += BK) {
    __syncthreads();
    const int colq = q * 8;
    if (MODE == 0) {
      int col = k0 + colq;
      const float4* s0 = (const float4*)(af0 + col);
      const float4* s1 = (const float4*)(af1 + col);
      float4 x0 = s0[0], y0 = s0[1];
      float4 x1 = s1[0], y1 = s1[1];
      union { u16 u[8]; bf16x8 v; } o0, o1;
      o0.u[0] = f2b(x0.x); o0.u[1] = f2b(x0.y); o0.u[2] = f2b(x0.z); o0.u[3] = f2b(x0.w);
      o0.u[4] = f2b(y0.x); o0.u[5] = f2b(y0.y); o0.u[6] = f2b(y0.z); o0.u[7] = f2b(y0.w);
      o1.u[0] = f2b(x1.x); o1.u[1] = f2b(x1.y); o1.u[2] = f2b(x1.z); o1.u[3] = f2b(x1.w);
      o1.u[4] = f2b(y1.x); o1.u[5] = f2b(y1.y); o1.u[6] = f2b(y1.z); o1.u[7] = f2b(y1.w);
      *(bf16x8*)&lA[(tid) * 8]       = o0.v;
      *(bf16x8*)&lA[(tid + 256) * 8] = o1.v;
    } else {
      int seg = k0 >> 9;                  // 0: left child, 1: right child, 2: u
      int col = (k0 & 511) + colq;
      const u16* g0 = (seg == 0 ? aL0 : (seg == 1 ? aR0 : aU0)) + col;
      const u16* g1 = (seg == 0 ? aL1 : (seg == 1 ? aR1 : aU1)) + col;
      glds16(g0, &lA[(tid) * 8]);
      glds16(g1, &lA[(tid + 256) * 8]);
    }
    {
      int col = k0 + colq;
      glds16(bp0 + col, &lB[(tid) * 8]);
      glds16(bp1 + col, &lB[(tid + 256) * 8]);
    }
    __syncthreads();

    bf16x8 av[4], bv[4];
#pragma unroll
    for (int i = 0; i < 4; i++) {
      av[i] = *(const bf16x8*)&lA[(wrow * 64 + i * 16 + fm) * BK + kk];
      bv[i] = *(const bf16x8*)&lB[(wcol * 64 + i * 16 + fm) * BK + kk];
    }
#pragma unroll
    for (int i = 0; i < 4; i++)
#pragma unroll
      for (int j = 0; j < 4; j++)
        acc[i][j] = __builtin_amdgcn_mfma_f32_16x16x32_bf16(av[i], bv[j], acc[i][j], 0, 0, 0);
  }

  // Epilogue: C/D layout col=lane&15, row=(lane>>4)*4+reg (m89-verified).
  const int r0 = (lane >> 4) * 4;
#pragma unroll
  for (int i = 0; i < 4; i++) {
    int mI = mBase + wrow * 64 + i * 16 + r0;
#pragma unroll
    for (int j = 0; j < 4; j++) {
      int col = n0 + wcol * 64 + j * 16 + fm;
      float bvv = bias[col];
#pragma unroll
      for (int r = 0; r < 4; r++) {
        int m = mI + r;
        if (m < M) {
          float v = acc[i][j][r] + bvv;
          v = v > 0.f ? v : 0.f;
          out[(size_t)m * 512 + col] = f2b(v);
        }
      }
    }
  }
}

__global__ void cvt_f32_to_bf16(const float* __restrict__ src, u16* __restrict__ dst, int n8) {
  int i = blockIdx.x * blockDim.x + threadIdx.x;
  if (i >= n8) return;
  const float4* s = (const float4*)src;
  float4 a = s[2 * i], b = s[2 * i + 1];
  union { u16 u[8]; bf16x8 v; } o;
  o.u[0] = f2b(a.x); o.u[1] = f2b(a.y); o.u[2] = f2b(a.z); o.u[3] = f2b(a.w);
  o.u[4] = f2b(b.x); o.u[5] = f2b(b.y); o.u[6] = f2b(b.z); o.u[7] = f2b(b.w);
  *(bf16x8*)(dst + (size_t)i * 8) = o.v;
}

__global__ void cvt_bf16_to_f32(const u16* __restrict__ src, float* __restrict__ dst, int n4) {
  int i = blockIdx.x * blockDim.x + threadIdx.x;
  if (i >= n4) return;
  uint2 p = ((const uint2*)src)[i];
  float4 o;
  o.x = b2f(p.x & 0xffffu); o.y = b2f(p.x >> 16);
  o.z = b2f(p.y & 0xffffu); o.w = b2f(p.y >> 16);
  ((float4*)dst)[i] = o;
}

extern "C" void kernel_launch(void* const* d_in, const int* in_sizes, int n_in,
                              void* d_out, int out_size, void* d_ws, size_t ws_size,
                              hipStream_t stream) {
  const float* contents = (const float*)d_in[0];
  const int2*  children = (const int2*)d_in[1];
  const float* W_u = (const float*)d_in[2];
  const float* b_u = (const float*)d_in[3];
  const float* W_h = (const float*)d_in[4];
  const float* b_h = (const float*)d_in[5];
  float* out = (float*)d_out;

  const int B = 64, D = 11, F = 256, H = 512;
  const int N = B * ((1 << D) - 1);          // 131008 nodes

  // Workspace layout (bytes): u_bf[N*H], Wub[H*F], Whb[H*3H], embA, embB
  char* ws = (char*)d_ws;
  u16* u_bf = (u16*)ws;
  size_t off = (size_t)N * H * 2;
  u16* Wub = (u16*)(ws + off); off += (size_t)H * F * 2;
  u16* Whb = (u16*)(ws + off); off += (size_t)H * 3 * H * 2;
  u16* embA = (u16*)(ws + off); off += (size_t)(B << (D - 2)) * H * 2;
  u16* embB = (u16*)(ws + off);

  // Weights -> bf16 (every call; no static state allowed)
  {
    int n8 = H * F / 8;
    cvt_f32_to_bf16<<<(n8 + 255) / 256, 256, 0, stream>>>(W_u, Wub, n8);
    n8 = H * 3 * H / 8;
    cvt_f32_to_bf16<<<(n8 + 255) / 256, 256, 0, stream>>>(W_h, Whb, n8);
  }

  // GEMM1: u = relu(contents @ W_u^T + b_u), fp32 A converted in staging
  {
    dim3 g(512 / TILE, (N + TILE - 1) / TILE);
    gemm_bt<0><<<g, 256, 0, stream>>>(contents, nullptr, nullptr, nullptr,
                                      Wub, b_u, u_bf, N, F);
  }

  // Tree levels j = D-2 .. 0
  const u16* embPrev = u_bf + (size_t)(B * ((1 << (D - 1)) - 1)) * H;  // leaves
  u16* dst = embA;
  for (int j = D - 2; j >= 0; --j) {
    int M = B << j;
    int o = B * ((1 << j) - 1);
    dim3 g(512 / TILE, (M + TILE - 1) / TILE);
    gemm_bt<1><<<g, 256, 0, stream>>>(nullptr, embPrev, u_bf + (size_t)o * H,
                                      children + o, Whb, b_h, dst, M, 3 * H);
    embPrev = dst;
    dst = (dst == embA) ? embB : embA;
  }

  // Level-0 emb (64 x 512) -> fp32 output
  {
    int n4 = B * H / 4;
    cvt_bf16_to_f32<<<(n4 + 255) / 256, 256, 0, stream>>>(embPrev, out, n4);
  }
}